// Round 6
// baseline (148.386 us; speedup 1.0000x reference)
//
#include <hip/hip_runtime.h>
#include <math.h>

#define D100 100
#define NE 50000
#define BATCH 16
#define EPS_F 1e-5f
#define TPT 782              // 64-row tiles per tensor (782*64 = 50048, zero-padded)
#define NB2 196              // gram blocks per tensor
#define TPB2 4               // tiles per gram block
#define SLICES 16

typedef __attribute__((ext_vector_type(8))) short short8;
typedef __attribute__((ext_vector_type(16))) float float16;
typedef unsigned short u16;

__device__ __forceinline__ u16 f2bf(float x) {   // RNE float->bf16
  union { float f; unsigned u; } c; c.f = x;
  unsigned r = c.u + 0x7FFFu + ((c.u >> 16) & 1u);
  return (u16)(r >> 16);
}
__device__ __forceinline__ float bf2f(u16 v) {
  return __uint_as_float(((unsigned)v) << 16);
}
__device__ __forceinline__ float f4get(const float4& v, int j) {
  switch (j) { case 0: return v.x; case 1: return v.y; case 2: return v.z; default: return v.w; }
}

// ---------------------------------------------------------------------------
// K1 fallback (monolithic)
__global__ void k1_wm(const float* __restrict__ W_re, const float* __restrict__ W_im,
                      const float* __restrict__ R2, const int* __restrict__ r_idx,
                      float* __restrict__ Wm) {
  const int t = blockIdx.y;
  const float* W = t ? W_im : W_re;
  int ef = blockIdx.x * 256 + threadIdx.x;
  if (ef >= 10000) return;
  int ridx[16];
#pragma unroll
  for (int b = 0; b < 16; b++) ridx[b] = r_idx[b];
  float acc[16];
#pragma unroll
  for (int b = 0; b < 16; b++) acc[b] = 0.f;
  for (int k = 0; k < 100; k++) {
    float w = W[k * 10000 + ef];
#pragma unroll
    for (int b = 0; b < 16; b++) acc[b] = fmaf(R2[ridx[b] * 100 + k], w, acc[b]);
  }
  float* o = Wm + t * 160000 + ef;
#pragma unroll
  for (int b = 0; b < 16; b++) o[b * 10000] = acc[b];
}

// K1a: split-K partials. grid (10, 4, 2), block 256
__global__ void k1a_wm(const float* __restrict__ W_re, const float* __restrict__ W_im,
                       const float* __restrict__ R2, const int* __restrict__ r_idx,
                       float* __restrict__ Wm_p) {
  const int t = blockIdx.z, kc = blockIdx.y;
  const float* W = t ? W_im : W_re;
  const float4* W4 = (const float4*)W;
  __shared__ float r2s[16][28];
  const int tid = threadIdx.x;
  for (int i = tid; i < 400; i += 256) {
    int b = i / 25, kk = i - b * 25;
    r2s[b][kk] = R2[r_idx[b] * 100 + kc * 25 + kk];
  }
  __syncthreads();
  int ef4 = blockIdx.x * 256 + tid;
  if (ef4 < 2500) {
    float4 acc[16];
#pragma unroll
    for (int b = 0; b < 16; b++) acc[b] = make_float4(0.f, 0.f, 0.f, 0.f);
#pragma unroll 5
    for (int kk = 0; kk < 25; kk++) {
      float4 w = W4[(kc * 25 + kk) * 2500 + ef4];
#pragma unroll
      for (int b = 0; b < 16; b++) {
        float r = r2s[b][kk];
        acc[b].x = fmaf(r, w.x, acc[b].x);
        acc[b].y = fmaf(r, w.y, acc[b].y);
        acc[b].z = fmaf(r, w.z, acc[b].z);
        acc[b].w = fmaf(r, w.w, acc[b].w);
      }
    }
    float4* o = (float4*)(Wm_p + (long)kc * 320000 + t * 160000);
#pragma unroll
    for (int b = 0; b < 16; b++) o[b * 2500 + ef4] = acc[b];
  }
}

// K1b: Wm = sum over 4 kc partials.  grid (313), block 256
__global__ void k1b_reduce(const float* __restrict__ Wm_p, float* __restrict__ Wm) {
  int i4 = blockIdx.x * 256 + threadIdx.x;
  if (i4 >= 80000) return;
  const float4* P4 = (const float4*)Wm_p;
  float4 a = P4[i4], b = P4[80000 + i4], c = P4[160000 + i4], d = P4[240000 + i4];
  float4 o;
  o.x = a.x + b.x + c.x + d.x;
  o.y = a.y + b.y + c.y + d.y;
  o.z = a.z + b.z + c.z + d.z;
  o.w = a.w + b.w + c.w + d.w;
  ((float4*)Wm)[i4] = o;
}

// ---------------------------------------------------------------------------
// K2f: fused transpose+cast+MFMA Gram.  grid (NB2, 2), block 256 (4 waves).
// LDS holds one 64-row tile in MFMA fragment-major bf16 layout; ds_read_b128
// is stride-1 across lanes (conflict-free).  Register-staged double pipeline.
__global__ __launch_bounds__(256) void k2f_gram(const float* __restrict__ E_a,
                                                const float* __restrict__ E_b,
                                                float* __restrict__ Gp,
                                                float* __restrict__ CSp) {
  const int t = blockIdx.y, bx = blockIdx.x;
  const float4* E4 = (const float4*)(t ? E_b : E_a);
  __shared__ __align__(16) u16 FRl[4][4][512];   // [rb][ncl][lane*8+elem], 16 KB
  const int tid = threadIdx.x;
  const int wave = tid >> 6, lane = tid & 63, l31 = lane & 31;

  for (int i = tid; i < 8192; i += 256) ((u16*)FRl)[i] = 0;   // rows e>=100 stay 0

  const int ti0 = bx * TPB2;
  const int nt = min(ti0 + TPB2, TPT) - ti0;

  float16 acc0, acc1, acc2, acc3;
#pragma unroll 16
  for (int r = 0; r < 16; r++) { acc0[r] = 0.f; acc1[r] = 0.f; acc2[r] = 0.f; acc3[r] = 0.f; }
  float cs = 0.f;
  float4 st[7];

#define K2F_LOAD(tile)                                          \
  { int n0 = (tile) * 64;                                       \
    _Pragma("unroll")                                           \
    for (int s = 0; s < 7; s++) {                               \
      int i = s * 256 + tid;                                    \
      float4 v = make_float4(0.f, 0.f, 0.f, 0.f);               \
      if (i < 1600) {                                           \
        int nl = i / 25, e4 = i - nl * 25;                      \
        int n = n0 + nl;                                        \
        if (n < NE) v = E4[(long)n * 25 + e4];                  \
      }                                                         \
      st[s] = v;                                                \
    } }

#define K2F_WRITE()                                             \
  { _Pragma("unroll")                                           \
    for (int s = 0; s < 7; s++) {                               \
      int i = s * 256 + tid;                                    \
      if (i < 1600) {                                           \
        int nl = i / 25, e4 = i - nl * 25;                      \
        int half = (nl >> 3) & 1, ncl = nl >> 4, elem = nl & 7; \
        _Pragma("unroll")                                       \
        for (int j = 0; j < 4; j++) {                           \
          int e = e4 * 4 + j;                                   \
          FRl[e >> 5][ncl][((e & 31) + 32 * half) * 8 + elem] = f2bf(f4get(st[s], j)); \
        } } } }

  __syncthreads();            // zeros visible
  K2F_LOAD(ti0);
  K2F_WRITE();
  __syncthreads();

  for (int tt = 0; tt < nt; tt++) {
    if (tt + 1 < nt) K2F_LOAD(ti0 + tt + 1);
#pragma unroll
    for (int ncl = 0; ncl < 4; ncl++) {
      const u16* pf = &FRl[0][ncl][lane * 8];
      short8 f0 = *(const short8*)pf;
      short8 f1 = *(const short8*)(pf + 2048);
      short8 f2 = *(const short8*)(pf + 4096);
      short8 f3 = *(const short8*)(pf + 6144);
      short8 av = *(const short8*)(pf + wave * 2048);
      acc0 = __builtin_amdgcn_mfma_f32_32x32x16_bf16(av, f0, acc0, 0, 0, 0);
      acc1 = __builtin_amdgcn_mfma_f32_32x32x16_bf16(av, f1, acc1, 0, 0, 0);
      acc2 = __builtin_amdgcn_mfma_f32_32x32x16_bf16(av, f2, acc2, 0, 0, 0);
      acc3 = __builtin_amdgcn_mfma_f32_32x32x16_bf16(av, f3, acc3, 0, 0, 0);
#pragma unroll
      for (int j = 0; j < 8; j++) cs += bf2f((u16)av[j]);
    }
    __syncthreads();
    if (tt + 1 < nt) K2F_WRITE();
    __syncthreads();
  }

  float* gp = Gp + ((long)t * NB2 + bx) * 10000;
#pragma unroll 16
  for (int r = 0; r < 16; r++) {
    int m = (r & 3) + 8 * (r >> 2) + 4 * (lane >> 5);   // verified C/D mapping
    int e = wave * 32 + m;
    if (e < 100) {
      gp[e * 100 + l31] = acc0[r];
      gp[e * 100 + 32 + l31] = acc1[r];
      gp[e * 100 + 64 + l31] = acc2[r];
      if (l31 < 4) gp[e * 100 + 96 + l31] = acc3[r];
    }
  }
  cs += __shfl_xor(cs, 32);
  int row = wave * 32 + l31;
  if (lane < 32 && row < 100)
    CSp[((long)t * NB2 + bx) * 100 + row] = cs;
}

// ---------------------------------------------------------------------------
// K2 fallback: VALU Gram (only if workspace too small)
__global__ __launch_bounds__(256, 4) void k2_gram(const float* __restrict__ E_a,
                                                  const float* __restrict__ E_b,
                                                  float* __restrict__ Gp,
                                                  float* __restrict__ CSp,
                                                  int NB, int RPB) {
  const int t = blockIdx.y;
  const float* E = t ? E_b : E_a;
  const float4* E4 = (const float4*)E;
  __shared__ float sm[32][128];
  const int tid = threadIdx.x;
  const int bx = blockIdx.x;
  int r0 = bx * RPB;
  int rend = min(r0 + RPB, NE);
  for (int i = tid; i < 32 * 28; i += 256) {
    int r = i / 28;
    sm[r][100 + (i - r * 28)] = 0.f;
  }
  float acc[8][8];
#pragma unroll
  for (int i = 0; i < 8; i++)
#pragma unroll
    for (int j = 0; j < 8; j++) acc[i][j] = 0.f;
  float cs = 0.f;
  const int ty = tid >> 4, tx = tid & 15;
  for (int base = r0; base < rend; base += 32) {
    int cnt = min(32, rend - base);
    __syncthreads();
    for (int i = tid; i < 800; i += 256) {
      int r = i / 25, c4 = i - r * 25;
      float4 v = make_float4(0.f, 0.f, 0.f, 0.f);
      if (r < cnt) v = E4[(long)(base + r) * 25 + c4];
      *(float4*)&sm[r][c4 * 4] = v;
    }
    __syncthreads();
#pragma unroll 2
    for (int r = 0; r < 32; r++) {
      float4 a0 = *(const float4*)&sm[r][ty * 8];
      float4 a1 = *(const float4*)&sm[r][ty * 8 + 4];
      float4 b0 = *(const float4*)&sm[r][tx * 8];
      float4 b1 = *(const float4*)&sm[r][tx * 8 + 4];
      float av[8] = {a0.x, a0.y, a0.z, a0.w, a1.x, a1.y, a1.z, a1.w};
      float bv[8] = {b0.x, b0.y, b0.z, b0.w, b1.x, b1.y, b1.z, b1.w};
#pragma unroll
      for (int i = 0; i < 8; i++)
#pragma unroll
        for (int j = 0; j < 8; j++) acc[i][j] = fmaf(av[i], bv[j], acc[i][j]);
    }
    if (tid < 100) {
#pragma unroll 4
      for (int r = 0; r < 32; r++) cs += sm[r][tid];
    }
  }
  float* gp = Gp + ((long)t * NB + bx) * 10000;
#pragma unroll
  for (int i = 0; i < 8; i++) {
    int e = ty * 8 + i;
    if (e < 100) {
#pragma unroll
      for (int j = 0; j < 8; j++) {
        int ep = tx * 8 + j;
        if (ep < 100) gp[e * 100 + ep] = acc[i][j];
      }
    }
  }
  if (tid < 100) CSp[((long)t * NB + bx) * 100 + tid] = cs;
}

// ---------------------------------------------------------------------------
// K3a/K3b: tree reduce of Gram + colsum partials
__global__ void k3a_reduce(const float* __restrict__ Gp, const float* __restrict__ CSp,
                           float* __restrict__ Gp2, float* __restrict__ CSp2,
                           int NB, int seg) {
  int chunk = blockIdx.x, slice = blockIdx.y, t = blockIdx.z;
  int nb0 = slice * seg;
  int nb1 = min(nb0 + seg, NB);
  int idx = chunk * 256 + threadIdx.x;
  if (idx < 10000) {
    float s = 0.f;
    const float* p = Gp + ((long)t * NB + nb0) * 10000 + idx;
    for (int nb = nb0; nb < nb1; nb++, p += 10000) s += *p;
    Gp2[(t * SLICES + slice) * 10000 + idx] = s;
  }
  if (chunk == 0 && threadIdx.x < 100) {
    float s = 0.f;
    const float* p = CSp + ((long)t * NB + nb0) * 100 + threadIdx.x;
    for (int nb = nb0; nb < nb1; nb++, p += 100) s += *p;
    CSp2[(t * SLICES + slice) * 100 + threadIdx.x] = s;
  }
}

__global__ void k3b_reduce(const float* __restrict__ Gp2, const float* __restrict__ CSp2,
                           float* __restrict__ G, float* __restrict__ CS) {
  int chunk = blockIdx.x, t = blockIdx.y;
  int idx = chunk * 256 + threadIdx.x;
  if (idx < 10000) {
    float s = 0.f;
    const float* p = Gp2 + (long)t * SLICES * 10000 + idx;
#pragma unroll
    for (int sl = 0; sl < SLICES; sl++) s += p[sl * 10000];
    G[t * 10000 + idx] = s;
  }
  if (chunk == 0 && threadIdx.x < 100) {
    float s = 0.f;
    const float* p = CSp2 + (long)t * SLICES * 100 + threadIdx.x;
#pragma unroll
    for (int sl = 0; sl < SLICES; sl++) s += p[sl * 100];
    CS[t * 100 + threadIdx.x] = s;
  }
}

// ---------------------------------------------------------------------------
// K6p: BN3 partial stats.  grid (8, 16, 2), block 256.
// s1p[t][b][c][f] = sum_{ep in chunk c} (sum_e G[e][ep] Wb[e][f]) * Wb[ep][f]
__global__ __launch_bounds__(256) void k6p_stats(const float* __restrict__ Wm,
                                                 const float* __restrict__ G,
                                                 const float* __restrict__ CS,
                                                 float* __restrict__ s1p,
                                                 float* __restrict__ s2p) {
  int c = blockIdx.x, b = blockIdx.y, t = blockIdx.z;
  int tid = threadIdx.x;
  int ep0 = c * 13;
  int ne = min(13, 100 - ep0);
  __shared__ float Gl[100][13];
  __shared__ float CSl[100];
  __shared__ float s1l[2][128];
  for (int i = tid; i < 1300; i += 256) {
    int e = i / 13, k = i - e * 13;
    Gl[e][k] = (ep0 + k < 100) ? G[t * 10000 + e * 100 + ep0 + k] : 0.f;
  }
  if (tid < 100) CSl[tid] = CS[t * 100 + tid];
  __syncthreads();
  int f = tid & 127, half = tid >> 7;
  int k0 = half ? 7 : 0;
  int kn = half ? ne - 7 : 7;
  const float* Wb = Wm + t * 160000 + b * 10000;
  float s1 = 0.f;
  if (f < 100) {
    float a[7];
#pragma unroll
    for (int k = 0; k < 7; k++) a[k] = 0.f;
    for (int e = 0; e < 100; e++) {
      float wv = Wb[e * 100 + f];
#pragma unroll
      for (int k = 0; k < 7; k++)
        if (k < kn) a[k] = fmaf(Gl[e][k0 + k], wv, a[k]);
    }
#pragma unroll
    for (int k = 0; k < 7; k++)
      if (k < kn) s1 += a[k] * Wb[(ep0 + k0 + k) * 100 + f];
  }
  s1l[half][f] = (f < 100) ? s1 : 0.f;
  __syncthreads();
  if (tid < 100)
    s1p[((t * 16 + b) * 8 + c) * 100 + tid] = s1l[0][tid] + s1l[1][tid];
  if (c == 0 && half == 0 && f < 100) {
    float s2 = 0.f;
    for (int e = 0; e < 100; e++) s2 = fmaf(Wb[e * 100 + f], CSl[e], s2);
    s2p[(t * 16 + b) * 100 + f] = s2;
  }
}

// ---------------------------------------------------------------------------
// K458: fused k4+k5+k8.  grid (16), block 256.  Each block redundantly
// computes the (tiny) BN chain for all batches, then finalizes its own b.
__global__ __launch_bounds__(256) void k458(const float* __restrict__ E_a,
                                            const float* __restrict__ E_b,
                                            const int* __restrict__ h_idx,
                                            const int* __restrict__ r_idx,
                                            const float* __restrict__ Wm,
                                            const float* __restrict__ g0r, const float* __restrict__ b0r,
                                            const float* __restrict__ g0i, const float* __restrict__ b0i,
                                            const float* __restrict__ g1r, const float* __restrict__ b1r,
                                            const float* __restrict__ g1i, const float* __restrict__ b1i,
                                            const float* __restrict__ R_re, const float* __restrict__ R_im,
                                            const float* __restrict__ s1p, const float* __restrict__ s2p,
                                            const float* __restrict__ gEa, const float* __restrict__ bEa,
                                            const float* __restrict__ gEb, const float* __restrict__ bEb,
                                            float* __restrict__ u, float* __restrict__ c) {
  int bo = blockIdx.x, tid = threadIdx.x;
  __shared__ float xa[1600], xb[1600];
  __shared__ float trw[3200];
  __shared__ float sca[200], shl[200];
  __shared__ float al[200], be[200];
  __shared__ float w0[100], w1[100], t01l[200], pc[128];

  // phase 1: gather h rows (all batches)
  for (int i = tid; i < 1600; i += 256) {
    int b = i / 100, e = i - b * 100;
    int h = h_idx[b];
    xa[i] = E_a[h * 100 + e];
    xb[i] = E_b[h * 100 + e];
  }
  __syncthreads();
  // phase 2: BN0 in place (thread e owns column e)
  if (tid < 100) {
    int e = tid;
    float m = 0.f, s = 0.f;
#pragma unroll
    for (int b = 0; b < 16; b++) { float v = xa[b * 100 + e]; m += v; s += v * v; }
    m *= (1.f / 16.f);
    float var = s * (1.f / 16.f) - m * m;
    float sc = rsqrtf(var + EPS_F) * g0r[e], sh = b0r[e] - m * sc;
#pragma unroll
    for (int b = 0; b < 16; b++) xa[b * 100 + e] = xa[b * 100 + e] * sc + sh;
    m = 0.f; s = 0.f;
#pragma unroll
    for (int b = 0; b < 16; b++) { float v = xb[b * 100 + e]; m += v; s += v * v; }
    m *= (1.f / 16.f);
    var = s * (1.f / 16.f) - m * m;
    sc = rsqrtf(var + EPS_F) * g0i[e]; sh = b0i[e] - m * sc;
#pragma unroll
    for (int b = 0; b < 16; b++) xb[b * 100 + e] = xb[b * 100 + e] * sc + sh;
  }
  __syncthreads();
  // phase 3: traw for all (t,b,f)
  for (int idx = tid; idx < 3200; idx += 256) {
    int tt = idx / 1600, rem = idx - tt * 1600, b = rem / 100, f = rem - b * 100;
    const float* W = Wm + tt * 160000 + b * 10000 + f;
    const float* x = (tt ? xb : xa) + b * 100;
    float s = 0.f;
    for (int e = 0; e < 100; e++) s = fmaf(x[e], W[e * 100], s);
    trw[idx] = s;
  }
  __syncthreads();
  // phase 4: BN1 scale/shift per (t,f)
  if (tid < 200) {
    int tt = tid / 100, f = tid - tt * 100;
    float m = 0.f, s = 0.f;
#pragma unroll
    for (int b = 0; b < 16; b++) { float v = trw[tt * 1600 + b * 100 + f]; m += v; s += v * v; }
    m *= (1.f / 16.f);
    float var = s * (1.f / 16.f) - m * m;
    float g = tt ? g1i[f] : g1r[f];
    float bb = tt ? b1i[f] : b1r[f];
    float sc = rsqrtf(var + EPS_F) * g;
    sca[tid] = sc; shl[tid] = bb - m * sc;
  }
  __syncthreads();
  // phase 4b: Mobius for own bo
  if (tid < 100) {
    int f = tid;
    float va = trw[bo * 100 + f] * sca[f] + shl[f];
    float vb = trw[1600 + bo * 100 + f] * sca[100 + f] + shl[100 + f];
    int base = r_idx[bo] * 400 + f;
    float ra0 = R_re[base],       ra1 = R_im[base];
    float rb0 = R_re[base + 100], rb1 = R_im[base + 100];
    float rc0 = R_re[base + 200], rc1 = R_im[base + 200];
    float rd0 = R_re[base + 300], rd1 = R_im[base + 300];
    float top0 = va * ra0 - vb * ra1 + rb0;
    float top1 = va * ra1 + vb * ra0 + rb1;
    float bot0 = va * rc0 - vb * rc1 + rd0;
    float bot1 = va * rc1 + vb * rc0 + rd1;
    float den = bot0 * bot0 + bot1 * bot1;
    t01l[f]       = (top0 * bot0 + top1 * bot1) / den;
    t01l[100 + f] = (top1 * bot0 - top0 * bot1) / den;
  }
  // phase 5: alpha/beta from BN3 partials
  if (tid < 200) {
    int tt = tid / 100, f = tid - tt * 100;
    float s1 = 0.f;
    for (int q = 0; q < 128; q++) s1 += s1p[tt * 12800 + q * 100 + f];
    float s2 = 0.f;
#pragma unroll
    for (int b2 = 0; b2 < 16; b2++) s2 += s2p[tt * 1600 + b2 * 100 + f];
    float mean = s2 * (1.f / 800000.f);
    float var = s1 * (1.f / 800000.f) - mean * mean;
    float g = tt ? gEb[f] : gEa[f];
    float bb = tt ? bEb[f] : bEa[f];
    float aa = rsqrtf(var + EPS_F) * g;
    al[tid] = aa;
    be[tid] = bb - mean * aa;
  }
  __syncthreads();
  // phase 6: w0/w1 + bias c[bo]
  float p = 0.f;
  if (tid < 100) {
    float t0 = t01l[tid], t1 = t01l[100 + tid];
    w0[tid] = t0 * al[tid];
    w1[tid] = t1 * al[100 + tid];
    p = t0 * be[tid] + t1 * be[100 + tid];
  }
  if (tid < 128) pc[tid] = (tid < 100) ? p : 0.f;
  __syncthreads();
  for (int o = 64; o > 0; o >>= 1) {
    if (tid < o) pc[tid] += pc[tid + o];
    __syncthreads();
  }
  if (tid == 0) c[bo] = pc[0];
  // phase 7: u
  if (tid < 100) {
    float sa = 0.f, sb = 0.f;
    const float* wa = Wm + bo * 10000 + tid * 100;
    const float* wb = Wm + 160000 + bo * 10000 + tid * 100;
    for (int f = 0; f < 100; f++) {
      sa = fmaf(w0[f], wa[f], sa);
      sb = fmaf(w1[f], wb[f], sb);
    }
    u[tid * 16 + bo] = sa;
    u[(100 + tid) * 16 + bo] = sb;
  }
}

// ---------------------------------------------------------------------------
// K9: score = sigmoid(c + u_a·E_a + u_b·E_b).  grid (196), block 256
__global__ __launch_bounds__(256) void k9_score(const float* __restrict__ E_a,
                                                const float* __restrict__ E_b,
                                                const float* __restrict__ u,
                                                const float* __restrict__ c,
                                                float* __restrict__ out) {
  int n = blockIdx.x * 256 + threadIdx.x;
  if (n >= NE) return;
  const float4* Ea4 = (const float4*)E_a;
  const float4* Eb4 = (const float4*)E_b;
  float acc[16];
#pragma unroll
  for (int b = 0; b < 16; b++) acc[b] = 0.f;
  for (int e4 = 0; e4 < 25; e4++) {
    float4 va = Ea4[n * 25 + e4];
    float4 vb = Eb4[n * 25 + e4];
    const float* ua = u + e4 * 64;
    const float* ub = u + 1600 + e4 * 64;
#pragma unroll
    for (int j = 0; j < 4; j++) {
      float fa = f4get(va, j);
      float fb = f4get(vb, j);
#pragma unroll
      for (int b = 0; b < 16; b++) {
        acc[b] = fmaf(ua[j * 16 + b], fa, acc[b]);
        acc[b] = fmaf(ub[j * 16 + b], fb, acc[b]);
      }
    }
  }
#pragma unroll
  for (int b = 0; b < 16; b++) {
    float x = acc[b] + c[b];
    out[b * NE + n] = 1.f / (1.f + expf(-x));
  }
}

// ---------------------------------------------------------------------------
extern "C" void kernel_launch(void* const* d_in, const int* in_sizes, int n_in,
                              void* d_out, int out_size, void* d_ws, size_t ws_size,
                              hipStream_t stream) {
  const int* h_idx = (const int*)d_in[0];
  const int* r_idx = (const int*)d_in[1];
  const float* E_a = (const float*)d_in[2];
  const float* E_b = (const float*)d_in[3];
  const float* R_re = (const float*)d_in[4];
  const float* R_im = (const float*)d_in[5];
  const float* R2 = (const float*)d_in[6];
  const float* W_re = (const float*)d_in[7];
  const float* W_im = (const float*)d_in[8];
  const float* g0r = (const float*)d_in[9];
  const float* b0r = (const float*)d_in[10];
  const float* g1r = (const float*)d_in[11];
  const float* b1r = (const float*)d_in[12];
  const float* g0i = (const float*)d_in[13];
  const float* b0i = (const float*)d_in[14];
  const float* g1i = (const float*)d_in[15];
  const float* b1i = (const float*)d_in[16];
  const float* gEa = (const float*)d_in[17];
  const float* bEa = (const float*)d_in[18];
  const float* gEb = (const float*)d_in[19];
  const float* bEb = (const float*)d_in[20];
  float* out = (float*)d_out;
  float* ws = (float*)d_ws;

  // fixed regions (372,216 floats)
  float* Wm = ws;                    // [2][16][10000]   320000
  float* G = Wm + 320000;            // [2][10000]        20000
  float* CS = G + 20000;             // [2][100]            200
  float* u = CS + 200;               // [2][100][16]       3200
  float* c = u + 3200;               //                      16
  float* s1p = c + 16;               // [2][16][8][100]   25600
  float* s2p = s1p + 25600;          // [2][16][100]       3200
  const long fixed = 372216;

  float* un = ws + fixed;
  long avail = (long)(ws_size / 4);
  long unionFloats = avail - fixed - 64;

  // k1 scratch overlaps union head (lifetime ends before gram)
  float* Wm_p = un;                  // 1,280,000 floats
  int splitK1 = (unionFloats >= 1280000);
  if (splitK1) {
    hipLaunchKernelGGL(k1a_wm, dim3(10, 4, 2), dim3(256), 0, stream, W_re, W_im, R2, r_idx, Wm_p);
    hipLaunchKernelGGL(k1b_reduce, dim3(313), dim3(256), 0, stream, Wm_p, Wm);
  } else {
    hipLaunchKernelGGL(k1_wm, dim3(40, 2), dim3(256), 0, stream, W_re, W_im, R2, r_idx, Wm);
  }

  const long needMain = 323200 + (long)NB2 * 20200;   // Gp2/CSp2 + Gp/CSp
  if (unionFloats >= needMain) {
    float* Gp2 = un;
    float* CSp2 = Gp2 + 320000;
    float* Gp = CSp2 + 3200;
    float* CSp = Gp + (long)NB2 * 20000;
    int seg = (NB2 + SLICES - 1) / SLICES;
    hipLaunchKernelGGL(k2f_gram, dim3(NB2, 2), dim3(256), 0, stream, E_a, E_b, Gp, CSp);
    hipLaunchKernelGGL(k3a_reduce, dim3(40, SLICES, 2), dim3(256), 0, stream,
                       Gp, CSp, Gp2, CSp2, NB2, seg);
    hipLaunchKernelGGL(k3b_reduce, dim3(40, 2), dim3(256), 0, stream, Gp2, CSp2, G, CS);
  } else {
    float* Gp2 = un;
    float* CSp2 = Gp2 + 320000;
    float* Gp = CSp2 + 3200;
    long room = (unionFloats - 323200) / 20200;
    int NB = room < 360 ? (int)room : 360;
    if (NB < 1) NB = 1;
    int RPB = (NE + NB - 1) / NB;
    int seg = (NB + SLICES - 1) / SLICES;
    float* CSp = Gp + (long)NB * 20000;
    hipLaunchKernelGGL(k2_gram, dim3(NB, 2), dim3(256), 0, stream, E_a, E_b, Gp, CSp, NB, RPB);
    hipLaunchKernelGGL(k3a_reduce, dim3(40, SLICES, 2), dim3(256), 0, stream,
                       Gp, CSp, Gp2, CSp2, NB, seg);
    hipLaunchKernelGGL(k3b_reduce, dim3(40, 2), dim3(256), 0, stream, Gp2, CSp2, G, CS);
  }

  hipLaunchKernelGGL(k6p_stats, dim3(8, 16, 2), dim3(256), 0, stream, Wm, G, CS, s1p, s2p);
  hipLaunchKernelGGL(k458, dim3(16), dim3(256), 0, stream, E_a, E_b, h_idx, r_idx, Wm,
                     g0r, b0r, g0i, b0i, g1r, b1r, g1i, b1i, R_re, R_im,
                     s1p, s2p, gEa, bEa, gEb, bEb, u, c);
  hipLaunchKernelGGL(k9_score, dim3((NE + 255) / 256), dim3(256), 0, stream,
                     E_a, E_b, u, c, out);
}

// Round 7
// 132.058 us; speedup vs baseline: 1.1236x; 1.1236x over previous
//
#include <hip/hip_runtime.h>
#include <math.h>

#define D100 100
#define NE 50000
#define BATCH 16
#define EPS_F 1e-5f
#define TPT 782              // 64-row tiles per tensor (782*64 = 50048, zero-padded)
#define NB2 196              // gram blocks per tensor
#define TPB2 4               // tiles per gram block
#define SLICES 16

typedef __attribute__((ext_vector_type(8))) short short8;
typedef __attribute__((ext_vector_type(16))) float float16;
typedef unsigned short u16;

__device__ __forceinline__ u16 f2bf(float x) {   // RNE float->bf16
  union { float f; unsigned u; } c; c.f = x;
  unsigned r = c.u + 0x7FFFu + ((c.u >> 16) & 1u);
  return (u16)(r >> 16);
}
__device__ __forceinline__ float bf2f(u16 v) {
  return __uint_as_float(((unsigned)v) << 16);
}
__device__ __forceinline__ float f4get(const float4& v, int j) {
  switch (j) { case 0: return v.x; case 1: return v.y; case 2: return v.z; default: return v.w; }
}

// ---------------------------------------------------------------------------
// K1 fallback (monolithic)
__global__ void k1_wm(const float* __restrict__ W_re, const float* __restrict__ W_im,
                      const float* __restrict__ R2, const int* __restrict__ r_idx,
                      float* __restrict__ Wm) {
  const int t = blockIdx.y;
  const float* W = t ? W_im : W_re;
  int ef = blockIdx.x * 256 + threadIdx.x;
  if (ef >= 10000) return;
  int ridx[16];
#pragma unroll
  for (int b = 0; b < 16; b++) ridx[b] = r_idx[b];
  float acc[16];
#pragma unroll
  for (int b = 0; b < 16; b++) acc[b] = 0.f;
  for (int k = 0; k < 100; k++) {
    float w = W[k * 10000 + ef];
#pragma unroll
    for (int b = 0; b < 16; b++) acc[b] = fmaf(R2[ridx[b] * 100 + k], w, acc[b]);
  }
  float* o = Wm + t * 160000 + ef;
#pragma unroll
  for (int b = 0; b < 16; b++) o[b * 10000] = acc[b];
}

// K1a: split-K partials. grid (10, 10, 2), block 256 — 400 blocks for BW
__global__ void k1a_wm(const float* __restrict__ W_re, const float* __restrict__ W_im,
                       const float* __restrict__ R2, const int* __restrict__ r_idx,
                       float* __restrict__ Wm_p) {
  const int t = blockIdx.z, kc = blockIdx.y;
  const float* W = t ? W_im : W_re;
  const float4* W4 = (const float4*)W;
  __shared__ float r2s[16][12];
  const int tid = threadIdx.x;
  for (int i = tid; i < 160; i += 256) {
    int b = i / 10, kk = i - b * 10;
    r2s[b][kk] = R2[r_idx[b] * 100 + kc * 10 + kk];
  }
  __syncthreads();
  int ef4 = blockIdx.x * 256 + tid;
  if (ef4 < 2500) {
    float4 acc[16];
#pragma unroll
    for (int b = 0; b < 16; b++) acc[b] = make_float4(0.f, 0.f, 0.f, 0.f);
#pragma unroll
    for (int kk = 0; kk < 10; kk++) {
      float4 w = W4[(kc * 10 + kk) * 2500 + ef4];
#pragma unroll
      for (int b = 0; b < 16; b++) {
        float r = r2s[b][kk];
        acc[b].x = fmaf(r, w.x, acc[b].x);
        acc[b].y = fmaf(r, w.y, acc[b].y);
        acc[b].z = fmaf(r, w.z, acc[b].z);
        acc[b].w = fmaf(r, w.w, acc[b].w);
      }
    }
    float4* o = (float4*)(Wm_p + (long)kc * 320000 + t * 160000);
#pragma unroll
    for (int b = 0; b < 16; b++) o[b * 2500 + ef4] = acc[b];
  }
}

// K1b: Wm = sum over 10 kc partials.  grid (313), block 256
__global__ void k1b_reduce(const float* __restrict__ Wm_p, float* __restrict__ Wm) {
  int i4 = blockIdx.x * 256 + threadIdx.x;
  if (i4 >= 80000) return;
  const float4* P4 = (const float4*)Wm_p;
  float4 o = make_float4(0.f, 0.f, 0.f, 0.f);
#pragma unroll
  for (int j = 0; j < 10; j++) {
    float4 a = P4[(long)j * 80000 + i4];
    o.x += a.x; o.y += a.y; o.z += a.z; o.w += a.w;
  }
  ((float4*)Wm)[i4] = o;
}

// ---------------------------------------------------------------------------
// K2f: fused transpose+cast+MFMA Gram.  grid (NB2, 2), block 256 (4 waves).
__global__ __launch_bounds__(256) void k2f_gram(const float* __restrict__ E_a,
                                                const float* __restrict__ E_b,
                                                float* __restrict__ Gp,
                                                float* __restrict__ CSp) {
  const int t = blockIdx.y, bx = blockIdx.x;
  const float4* E4 = (const float4*)(t ? E_b : E_a);
  __shared__ __align__(16) u16 FRl[4][4][512];   // [rb][ncl][lane*8+elem], 16 KB
  const int tid = threadIdx.x;
  const int wave = tid >> 6, lane = tid & 63, l31 = lane & 31;

  for (int i = tid; i < 8192; i += 256) ((u16*)FRl)[i] = 0;   // rows e>=100 stay 0

  const int ti0 = bx * TPB2;
  const int nt = min(ti0 + TPB2, TPT) - ti0;

  float16 acc0, acc1, acc2, acc3;
#pragma unroll 16
  for (int r = 0; r < 16; r++) { acc0[r] = 0.f; acc1[r] = 0.f; acc2[r] = 0.f; acc3[r] = 0.f; }
  float cs = 0.f;
  float4 st[7];

#define K2F_LOAD(tile)                                          \
  { int n0 = (tile) * 64;                                       \
    _Pragma("unroll")                                           \
    for (int s = 0; s < 7; s++) {                               \
      int i = s * 256 + tid;                                    \
      float4 v = make_float4(0.f, 0.f, 0.f, 0.f);               \
      if (i < 1600) {                                           \
        int nl = i / 25, e4 = i - nl * 25;                      \
        int n = n0 + nl;                                        \
        if (n < NE) v = E4[(long)n * 25 + e4];                  \
      }                                                         \
      st[s] = v;                                                \
    } }

#define K2F_WRITE()                                             \
  { _Pragma("unroll")                                           \
    for (int s = 0; s < 7; s++) {                               \
      int i = s * 256 + tid;                                    \
      if (i < 1600) {                                           \
        int nl = i / 25, e4 = i - nl * 25;                      \
        int half = (nl >> 3) & 1, ncl = nl >> 4, elem = nl & 7; \
        _Pragma("unroll")                                       \
        for (int j = 0; j < 4; j++) {                           \
          int e = e4 * 4 + j;                                   \
          FRl[e >> 5][ncl][((e & 31) + 32 * half) * 8 + elem] = f2bf(f4get(st[s], j)); \
        } } } }

  __syncthreads();            // zeros visible
  K2F_LOAD(ti0);
  K2F_WRITE();
  __syncthreads();

  for (int tt = 0; tt < nt; tt++) {
    if (tt + 1 < nt) K2F_LOAD(ti0 + tt + 1);
#pragma unroll
    for (int ncl = 0; ncl < 4; ncl++) {
      const u16* pf = &FRl[0][ncl][lane * 8];
      short8 f0 = *(const short8*)pf;
      short8 f1 = *(const short8*)(pf + 2048);
      short8 f2 = *(const short8*)(pf + 4096);
      short8 f3 = *(const short8*)(pf + 6144);
      short8 av = *(const short8*)(pf + wave * 2048);
      acc0 = __builtin_amdgcn_mfma_f32_32x32x16_bf16(av, f0, acc0, 0, 0, 0);
      acc1 = __builtin_amdgcn_mfma_f32_32x32x16_bf16(av, f1, acc1, 0, 0, 0);
      acc2 = __builtin_amdgcn_mfma_f32_32x32x16_bf16(av, f2, acc2, 0, 0, 0);
      acc3 = __builtin_amdgcn_mfma_f32_32x32x16_bf16(av, f3, acc3, 0, 0, 0);
#pragma unroll
      for (int j = 0; j < 8; j++) cs += bf2f((u16)av[j]);
    }
    __syncthreads();
    if (tt + 1 < nt) K2F_WRITE();
    __syncthreads();
  }

  float* gp = Gp + ((long)t * NB2 + bx) * 10000;
#pragma unroll 16
  for (int r = 0; r < 16; r++) {
    int m = (r & 3) + 8 * (r >> 2) + 4 * (lane >> 5);   // verified C/D mapping
    int e = wave * 32 + m;
    if (e < 100) {
      gp[e * 100 + l31] = acc0[r];
      gp[e * 100 + 32 + l31] = acc1[r];
      gp[e * 100 + 64 + l31] = acc2[r];
      if (l31 < 4) gp[e * 100 + 96 + l31] = acc3[r];
    }
  }
  cs += __shfl_xor(cs, 32);
  int row = wave * 32 + l31;
  if (lane < 32 && row < 100)
    CSp[((long)t * NB2 + bx) * 100 + row] = cs;
}

// ---------------------------------------------------------------------------
// K2 fallback: VALU Gram (only if workspace too small)
__global__ __launch_bounds__(256, 4) void k2_gram(const float* __restrict__ E_a,
                                                  const float* __restrict__ E_b,
                                                  float* __restrict__ Gp,
                                                  float* __restrict__ CSp,
                                                  int NB, int RPB) {
  const int t = blockIdx.y;
  const float* E = t ? E_b : E_a;
  const float4* E4 = (const float4*)E;
  __shared__ float sm[32][128];
  const int tid = threadIdx.x;
  const int bx = blockIdx.x;
  int r0 = bx * RPB;
  int rend = min(r0 + RPB, NE);
  for (int i = tid; i < 32 * 28; i += 256) {
    int r = i / 28;
    sm[r][100 + (i - r * 28)] = 0.f;
  }
  float acc[8][8];
#pragma unroll
  for (int i = 0; i < 8; i++)
#pragma unroll
    for (int j = 0; j < 8; j++) acc[i][j] = 0.f;
  float cs = 0.f;
  const int ty = tid >> 4, tx = tid & 15;
  for (int base = r0; base < rend; base += 32) {
    int cnt = min(32, rend - base);
    __syncthreads();
    for (int i = tid; i < 800; i += 256) {
      int r = i / 25, c4 = i - r * 25;
      float4 v = make_float4(0.f, 0.f, 0.f, 0.f);
      if (r < cnt) v = E4[(long)(base + r) * 25 + c4];
      *(float4*)&sm[r][c4 * 4] = v;
    }
    __syncthreads();
#pragma unroll 2
    for (int r = 0; r < 32; r++) {
      float4 a0 = *(const float4*)&sm[r][ty * 8];
      float4 a1 = *(const float4*)&sm[r][ty * 8 + 4];
      float4 b0 = *(const float4*)&sm[r][tx * 8];
      float4 b1 = *(const float4*)&sm[r][tx * 8 + 4];
      float av[8] = {a0.x, a0.y, a0.z, a0.w, a1.x, a1.y, a1.z, a1.w};
      float bv[8] = {b0.x, b0.y, b0.z, b0.w, b1.x, b1.y, b1.z, b1.w};
#pragma unroll
      for (int i = 0; i < 8; i++)
#pragma unroll
        for (int j = 0; j < 8; j++) acc[i][j] = fmaf(av[i], bv[j], acc[i][j]);
    }
    if (tid < 100) {
#pragma unroll 4
      for (int r = 0; r < 32; r++) cs += sm[r][tid];
    }
  }
  float* gp = Gp + ((long)t * NB + bx) * 10000;
#pragma unroll
  for (int i = 0; i < 8; i++) {
    int e = ty * 8 + i;
    if (e < 100) {
#pragma unroll
      for (int j = 0; j < 8; j++) {
        int ep = tx * 8 + j;
        if (ep < 100) gp[e * 100 + ep] = acc[i][j];
      }
    }
  }
  if (tid < 100) CSp[((long)t * NB + bx) * 100 + tid] = cs;
}

// ---------------------------------------------------------------------------
// K3a/K3b: tree reduce of Gram + colsum partials
__global__ void k3a_reduce(const float* __restrict__ Gp, const float* __restrict__ CSp,
                           float* __restrict__ Gp2, float* __restrict__ CSp2,
                           int NB, int seg) {
  int chunk = blockIdx.x, slice = blockIdx.y, t = blockIdx.z;
  int nb0 = slice * seg;
  int nb1 = min(nb0 + seg, NB);
  int idx = chunk * 256 + threadIdx.x;
  if (idx < 10000) {
    float s = 0.f;
    const float* p = Gp + ((long)t * NB + nb0) * 10000 + idx;
    for (int nb = nb0; nb < nb1; nb++, p += 10000) s += *p;
    Gp2[(t * SLICES + slice) * 10000 + idx] = s;
  }
  if (chunk == 0 && threadIdx.x < 100) {
    float s = 0.f;
    const float* p = CSp + ((long)t * NB + nb0) * 100 + threadIdx.x;
    for (int nb = nb0; nb < nb1; nb++, p += 100) s += *p;
    CSp2[(t * SLICES + slice) * 100 + threadIdx.x] = s;
  }
}

__global__ void k3b_reduce(const float* __restrict__ Gp2, const float* __restrict__ CSp2,
                           float* __restrict__ G, float* __restrict__ CS) {
  int chunk = blockIdx.x, t = blockIdx.y;
  int idx = chunk * 256 + threadIdx.x;
  if (idx < 10000) {
    float s = 0.f;
    const float* p = Gp2 + (long)t * SLICES * 10000 + idx;
#pragma unroll
    for (int sl = 0; sl < SLICES; sl++) s += p[sl * 10000];
    G[t * 10000 + idx] = s;
  }
  if (chunk == 0 && threadIdx.x < 100) {
    float s = 0.f;
    const float* p = CSp2 + (long)t * SLICES * 100 + threadIdx.x;
#pragma unroll
    for (int sl = 0; sl < SLICES; sl++) s += p[sl * 100];
    CS[t * 100 + threadIdx.x] = s;
  }
}

// ---------------------------------------------------------------------------
// K6p: BN3 partial stats.  grid (8, 16, 2), block 256.
__global__ __launch_bounds__(256) void k6p_stats(const float* __restrict__ Wm,
                                                 const float* __restrict__ G,
                                                 const float* __restrict__ CS,
                                                 float* __restrict__ s1p,
                                                 float* __restrict__ s2p) {
  int c = blockIdx.x, b = blockIdx.y, t = blockIdx.z;
  int tid = threadIdx.x;
  int ep0 = c * 13;
  int ne = min(13, 100 - ep0);
  __shared__ float Gl[100][13];
  __shared__ float CSl[100];
  __shared__ float s1l[2][128];
  for (int i = tid; i < 1300; i += 256) {
    int e = i / 13, k = i - e * 13;
    Gl[e][k] = (ep0 + k < 100) ? G[t * 10000 + e * 100 + ep0 + k] : 0.f;
  }
  if (tid < 100) CSl[tid] = CS[t * 100 + tid];
  __syncthreads();
  int f = tid & 127, half = tid >> 7;
  int k0 = half ? 7 : 0;
  int kn = half ? ne - 7 : 7;
  const float* Wb = Wm + t * 160000 + b * 10000;
  float s1 = 0.f;
  if (f < 100) {
    float a[7];
#pragma unroll
    for (int k = 0; k < 7; k++) a[k] = 0.f;
    for (int e = 0; e < 100; e++) {
      float wv = Wb[e * 100 + f];
#pragma unroll
      for (int k = 0; k < 7; k++)
        if (k < kn) a[k] = fmaf(Gl[e][k0 + k], wv, a[k]);
    }
#pragma unroll
    for (int k = 0; k < 7; k++)
      if (k < kn) s1 += a[k] * Wb[(ep0 + k0 + k) * 100 + f];
  }
  s1l[half][f] = (f < 100) ? s1 : 0.f;
  __syncthreads();
  if (tid < 100)
    s1p[((t * 16 + b) * 8 + c) * 100 + tid] = s1l[0][tid] + s1l[1][tid];
  if (c == 0 && half == 0 && f < 100) {
    float s2 = 0.f;
    for (int e = 0; e < 100; e++) s2 = fmaf(Wb[e * 100 + f], CSl[e], s2);
    s2p[(t * 16 + b) * 100 + f] = s2;
  }
}

// ---------------------------------------------------------------------------
// K4a: gather+BN0 (tiny redundant) + coalesced matvec -> traw; fold s1p c-sum.
// grid (32) = (t,b), block 128.
__global__ __launch_bounds__(128) void k4a_traw(const float* __restrict__ E_a,
                                                const float* __restrict__ E_b,
                                                const int* __restrict__ h_idx,
                                                const float* __restrict__ Wm,
                                                const float* __restrict__ g0r, const float* __restrict__ b0r,
                                                const float* __restrict__ g0i, const float* __restrict__ b0i,
                                                const float* __restrict__ s1p,
                                                float* __restrict__ traw,
                                                float* __restrict__ s1pp) {
  int bid = blockIdx.x;
  int t = bid >> 4, b = bid & 15;
  const float4* E4 = (const float4*)(t ? E_b : E_a);
  const float* g0 = t ? g0i : g0r;
  const float* be0 = t ? b0i : b0r;
  __shared__ float hrows[1600], x[100];
  int tid = threadIdx.x;
  for (int i = tid; i < 400; i += 128) {
    int b2 = i / 25, e4 = i - b2 * 25;
    float4 v = E4[(long)h_idx[b2] * 25 + e4];
    *(float4*)&hrows[b2 * 100 + e4 * 4] = v;
  }
  __syncthreads();
  if (tid < 100) {
    float m = 0.f, s = 0.f;
#pragma unroll
    for (int b2 = 0; b2 < 16; b2++) { float v = hrows[b2 * 100 + tid]; m += v; s += v * v; }
    m *= (1.f / 16.f);
    float var = s * (1.f / 16.f) - m * m;
    x[tid] = (hrows[b * 100 + tid] - m) * rsqrtf(var + EPS_F) * g0[tid] + be0[tid];
  }
  __syncthreads();
  if (tid < 100) {
    const float* W = Wm + t * 160000 + b * 10000 + tid;
    float s = 0.f;
    for (int e = 0; e < 100; e++) s = fmaf(x[e], W[e * 100], s);
    traw[t * 1600 + b * 100 + tid] = s;
    // fold the 8 ep-chunk partials so k4b only sums over b
    float s1 = 0.f;
    const float* p = s1p + ((t * 16 + b) * 8) * 100 + tid;
#pragma unroll
    for (int cc = 0; cc < 8; cc++) s1 += p[cc * 100];
    s1pp[t * 1600 + b * 100 + tid] = s1;
  }
}

// ---------------------------------------------------------------------------
// K4b: BN1 + Mobius + alpha/beta + w01 + c.  grid (1), block 256.  ~30 KB of IO.
__global__ __launch_bounds__(256) void k4b_mid(const float* __restrict__ traw,
                                               const int* __restrict__ r_idx,
                                               const float* __restrict__ g1r, const float* __restrict__ b1r,
                                               const float* __restrict__ g1i, const float* __restrict__ b1i,
                                               const float* __restrict__ R_re, const float* __restrict__ R_im,
                                               const float* __restrict__ s1pp, const float* __restrict__ s2p,
                                               const float* __restrict__ gEa, const float* __restrict__ bEa,
                                               const float* __restrict__ gEb, const float* __restrict__ bEb,
                                               float* __restrict__ w01, float* __restrict__ c) {
  int tid = threadIdx.x;
  __shared__ float tr[3200], t01l[3200];
  __shared__ float sca[200], shl[200], al[200], be[200];
  for (int i = tid; i < 3200; i += 256) tr[i] = traw[i];
  __syncthreads();
  if (tid < 200) {
    int tt = tid / 100, f = tid - tt * 100;
    float m = 0.f, s = 0.f;
#pragma unroll
    for (int b = 0; b < 16; b++) { float v = tr[tt * 1600 + b * 100 + f]; m += v; s += v * v; }
    m *= (1.f / 16.f);
    float var = s * (1.f / 16.f) - m * m;
    float g = tt ? g1i[f] : g1r[f];
    float bb = tt ? b1i[f] : b1r[f];
    float sc = rsqrtf(var + EPS_F) * g;
    sca[tid] = sc; shl[tid] = bb - m * sc;
    // alpha/beta
    float s1 = 0.f, s2 = 0.f;
#pragma unroll
    for (int b2 = 0; b2 < 16; b2++) {
      s1 += s1pp[tt * 1600 + b2 * 100 + f];
      s2 += s2p[tt * 1600 + b2 * 100 + f];
    }
    float mean = s2 * (1.f / 800000.f);
    float var2 = s1 * (1.f / 800000.f) - mean * mean;
    float gE = tt ? gEb[f] : gEa[f];
    float bE = tt ? bEb[f] : bEa[f];
    float aa = rsqrtf(var2 + EPS_F) * gE;
    al[tid] = aa; be[tid] = bE - mean * aa;
  }
  __syncthreads();
  for (int i = tid; i < 1600; i += 256) {
    int b = i / 100, f = i - b * 100;
    float va = tr[b * 100 + f] * sca[f] + shl[f];
    float vb = tr[1600 + b * 100 + f] * sca[100 + f] + shl[100 + f];
    int base = r_idx[b] * 400 + f;
    float ra0 = R_re[base],       ra1 = R_im[base];
    float rb0 = R_re[base + 100], rb1 = R_im[base + 100];
    float rc0 = R_re[base + 200], rc1 = R_im[base + 200];
    float rd0 = R_re[base + 300], rd1 = R_im[base + 300];
    float top0 = va * ra0 - vb * ra1 + rb0;
    float top1 = va * ra1 + vb * ra0 + rb1;
    float bot0 = va * rc0 - vb * rc1 + rd0;
    float bot1 = va * rc1 + vb * rc0 + rd1;
    float den = bot0 * bot0 + bot1 * bot1;
    float t0 = (top0 * bot0 + top1 * bot1) / den;
    float t1 = (top1 * bot0 - top0 * bot1) / den;
    t01l[i] = t0; t01l[1600 + i] = t1;
    w01[i] = t0 * al[f];
    w01[1600 + i] = t1 * al[100 + f];
  }
  __syncthreads();
  if (tid < 16) {
    float cc = 0.f;
    for (int f = 0; f < 100; f++) {
      cc += t01l[tid * 100 + f] * be[f] + t01l[1600 + tid * 100 + f] * be[100 + f];
    }
    c[tid] = cc;
  }
}

// ---------------------------------------------------------------------------
// K4c: u[t][e][b] = sum_f w01[t][b][f] * Wm[t][b][e][f].  grid (32), block 256.
// Wm tile LDS-staged, pad 101 -> conflict-free stride across lanes.
__global__ __launch_bounds__(256) void k4c_u(const float* __restrict__ Wm,
                                             const float* __restrict__ w01,
                                             float* __restrict__ u) {
  int bid = blockIdx.x;
  int t = bid >> 4, b = bid & 15;
  __shared__ float w[100];
  __shared__ float Wl[100 * 101];
  int tid = threadIdx.x;
  if (tid < 100) w[tid] = w01[t * 1600 + b * 100 + tid];
  const float4* W4 = (const float4*)(Wm + t * 160000 + b * 10000);
  for (int i = tid; i < 2500; i += 256) {
    float4 v = W4[i];
    int e = (i * 4) / 100, f0 = (i * 4) - e * 100;
    float* dst = &Wl[e * 101 + f0];
    dst[0] = v.x; dst[1] = v.y; dst[2] = v.z; dst[3] = v.w;
  }
  __syncthreads();
  if (tid < 100) {
    const float* row = &Wl[tid * 101];
    float s = 0.f;
    for (int f = 0; f < 100; f++) s = fmaf(w[f], row[f], s);
    u[(t * 100 + tid) * 16 + b] = s;
  }
}

// ---------------------------------------------------------------------------
// K9: score = sigmoid(c + u_a·E_a + u_b·E_b).  grid (196), block 256
__global__ __launch_bounds__(256) void k9_score(const float* __restrict__ E_a,
                                                const float* __restrict__ E_b,
                                                const float* __restrict__ u,
                                                const float* __restrict__ c,
                                                float* __restrict__ out) {
  int n = blockIdx.x * 256 + threadIdx.x;
  if (n >= NE) return;
  const float4* Ea4 = (const float4*)E_a;
  const float4* Eb4 = (const float4*)E_b;
  float acc[16];
#pragma unroll
  for (int b = 0; b < 16; b++) acc[b] = 0.f;
  for (int e4 = 0; e4 < 25; e4++) {
    float4 va = Ea4[n * 25 + e4];
    float4 vb = Eb4[n * 25 + e4];
    const float* ua = u + e4 * 64;
    const float* ub = u + 1600 + e4 * 64;
#pragma unroll
    for (int j = 0; j < 4; j++) {
      float fa = f4get(va, j);
      float fb = f4get(vb, j);
#pragma unroll
      for (int b = 0; b < 16; b++) {
        acc[b] = fmaf(ua[j * 16 + b], fa, acc[b]);
        acc[b] = fmaf(ub[j * 16 + b], fb, acc[b]);
      }
    }
  }
#pragma unroll
  for (int b = 0; b < 16; b++) {
    float x = acc[b] + c[b];
    out[b * NE + n] = 1.f / (1.f + expf(-x));
  }
}

// ---------------------------------------------------------------------------
extern "C" void kernel_launch(void* const* d_in, const int* in_sizes, int n_in,
                              void* d_out, int out_size, void* d_ws, size_t ws_size,
                              hipStream_t stream) {
  const int* h_idx = (const int*)d_in[0];
  const int* r_idx = (const int*)d_in[1];
  const float* E_a = (const float*)d_in[2];
  const float* E_b = (const float*)d_in[3];
  const float* R_re = (const float*)d_in[4];
  const float* R_im = (const float*)d_in[5];
  const float* R2 = (const float*)d_in[6];
  const float* W_re = (const float*)d_in[7];
  const float* W_im = (const float*)d_in[8];
  const float* g0r = (const float*)d_in[9];
  const float* b0r = (const float*)d_in[10];
  const float* g1r = (const float*)d_in[11];
  const float* b1r = (const float*)d_in[12];
  const float* g0i = (const float*)d_in[13];
  const float* b0i = (const float*)d_in[14];
  const float* g1i = (const float*)d_in[15];
  const float* b1i = (const float*)d_in[16];
  const float* gEa = (const float*)d_in[17];
  const float* bEa = (const float*)d_in[18];
  const float* gEb = (const float*)d_in[19];
  const float* bEb = (const float*)d_in[20];
  float* out = (float*)d_out;
  float* ws = (float*)d_ws;

  // fixed regions (381,816 floats)
  float* Wm = ws;                    // [2][16][10000]   320000
  float* G = Wm + 320000;            // [2][10000]        20000
  float* CS = G + 20000;             // [2][100]            200
  float* u = CS + 200;               // [2][100][16]       3200
  float* c = u + 3200;               //                      16
  float* s1p = c + 16;               // [2][16][8][100]   25600
  float* s2p = s1p + 25600;          // [2][16][100]       3200
  float* traw = s2p + 3200;          // [2][16][100]       3200
  float* w01 = traw + 3200;          // [2][16][100]       3200
  float* s1pp = w01 + 3200;          // [2][16][100]       3200
  const long fixed = 381816;

  float* un = ws + fixed;
  long avail = (long)(ws_size / 4);
  long unionFloats = avail - fixed - 64;

  // k1 scratch overlaps union head (lifetime ends before gram)
  float* Wm_p = un;                  // 3,200,000 floats
  int splitK1 = (unionFloats >= 3200000);
  if (splitK1) {
    hipLaunchKernelGGL(k1a_wm, dim3(10, 10, 2), dim3(256), 0, stream, W_re, W_im, R2, r_idx, Wm_p);
    hipLaunchKernelGGL(k1b_reduce, dim3(313), dim3(256), 0, stream, Wm_p, Wm);
  } else {
    hipLaunchKernelGGL(k1_wm, dim3(40, 2), dim3(256), 0, stream, W_re, W_im, R2, r_idx, Wm);
  }

  const long needMain = 323200 + (long)NB2 * 20200;   // Gp2/CSp2 + Gp/CSp
  if (unionFloats >= needMain) {
    float* Gp2 = un;
    float* CSp2 = Gp2 + 320000;
    float* Gp = CSp2 + 3200;
    float* CSp = Gp + (long)NB2 * 20000;
    int seg = (NB2 + SLICES - 1) / SLICES;
    hipLaunchKernelGGL(k2f_gram, dim3(NB2, 2), dim3(256), 0, stream, E_a, E_b, Gp, CSp);
    hipLaunchKernelGGL(k3a_reduce, dim3(40, SLICES, 2), dim3(256), 0, stream,
                       Gp, CSp, Gp2, CSp2, NB2, seg);
    hipLaunchKernelGGL(k3b_reduce, dim3(40, 2), dim3(256), 0, stream, Gp2, CSp2, G, CS);
  } else {
    float* Gp2 = un;
    float* CSp2 = Gp2 + 320000;
    float* Gp = CSp2 + 3200;
    long room = (unionFloats - 323200) / 20200;
    int NB = room < 360 ? (int)room : 360;
    if (NB < 1) NB = 1;
    int RPB = (NE + NB - 1) / NB;
    int seg = (NB + SLICES - 1) / SLICES;
    float* CSp = Gp + (long)NB * 20000;
    hipLaunchKernelGGL(k2_gram, dim3(NB, 2), dim3(256), 0, stream, E_a, E_b, Gp, CSp, NB, RPB);
    hipLaunchKernelGGL(k3a_reduce, dim3(40, SLICES, 2), dim3(256), 0, stream,
                       Gp, CSp, Gp2, CSp2, NB, seg);
    hipLaunchKernelGGL(k3b_reduce, dim3(40, 2), dim3(256), 0, stream, Gp2, CSp2, G, CS);
  }

  hipLaunchKernelGGL(k6p_stats, dim3(8, 16, 2), dim3(256), 0, stream, Wm, G, CS, s1p, s2p);
  hipLaunchKernelGGL(k4a_traw, dim3(32), dim3(128), 0, stream, E_a, E_b, h_idx, Wm,
                     g0r, b0r, g0i, b0i, s1p, traw, s1pp);
  hipLaunchKernelGGL(k4b_mid, dim3(1), dim3(256), 0, stream, traw, r_idx,
                     g1r, b1r, g1i, b1i, R_re, R_im, s1pp, s2p,
                     gEa, bEa, gEb, bEb, w01, c);
  hipLaunchKernelGGL(k4c_u, dim3(32), dim3(256), 0, stream, Wm, w01, u);
  hipLaunchKernelGGL(k9_score, dim3((NE + 255) / 256), dim3(256), 0, stream,
                     E_a, E_b, u, c, out);
}

// Round 8
// 97.130 us; speedup vs baseline: 1.5277x; 1.3596x over previous
//
#include <hip/hip_runtime.h>
#include <math.h>

#define D100 100
#define NE 50000
#define BATCH 16
#define EPS_F 1e-5f
#define TPT 782              // 64-row tiles per tensor (782*64 = 50048, zero-padded)
#define NB2 196              // gram blocks per tensor
#define TPB2 4               // tiles per gram block
#define SLICES 16
#define QCI 10               // e-rows per k6g block
#define QNJ 1664             // padded column count (13*128)

typedef __attribute__((ext_vector_type(8))) short short8;
typedef __attribute__((ext_vector_type(16))) float float16;
typedef unsigned short u16;

__device__ __forceinline__ u16 f2bf(float x) {   // RNE float->bf16
  union { float f; unsigned u; } c; c.f = x;
  unsigned r = c.u + 0x7FFFu + ((c.u >> 16) & 1u);
  return (u16)(r >> 16);
}
__device__ __forceinline__ float bf2f(u16 v) {
  return __uint_as_float(((unsigned)v) << 16);
}
__device__ __forceinline__ float f4get(const float4& v, int j) {
  switch (j) { case 0: return v.x; case 1: return v.y; case 2: return v.z; default: return v.w; }
}

// ---------------------------------------------------------------------------
// K1 fallback (monolithic)
__global__ void k1_wm(const float* __restrict__ W_re, const float* __restrict__ W_im,
                      const float* __restrict__ R2, const int* __restrict__ r_idx,
                      float* __restrict__ Wm) {
  const int t = blockIdx.y;
  const float* W = t ? W_im : W_re;
  int ef = blockIdx.x * 256 + threadIdx.x;
  if (ef >= 10000) return;
  int ridx[16];
#pragma unroll
  for (int b = 0; b < 16; b++) ridx[b] = r_idx[b];
  float acc[16];
#pragma unroll
  for (int b = 0; b < 16; b++) acc[b] = 0.f;
  for (int k = 0; k < 100; k++) {
    float w = W[k * 10000 + ef];
#pragma unroll
    for (int b = 0; b < 16; b++) acc[b] = fmaf(R2[ridx[b] * 100 + k], w, acc[b]);
  }
  float* o = Wm + t * 160000 + ef;
#pragma unroll
  for (int b = 0; b < 16; b++) o[b * 10000] = acc[b];
}

// K1a: split-K partials. grid (10, 10, 2), block 256
__global__ void k1a_wm(const float* __restrict__ W_re, const float* __restrict__ W_im,
                       const float* __restrict__ R2, const int* __restrict__ r_idx,
                       float* __restrict__ Wm_p) {
  const int t = blockIdx.z, kc = blockIdx.y;
  const float* W = t ? W_im : W_re;
  const float4* W4 = (const float4*)W;
  __shared__ float r2s[16][12];
  const int tid = threadIdx.x;
  for (int i = tid; i < 160; i += 256) {
    int b = i / 10, kk = i - b * 10;
    r2s[b][kk] = R2[r_idx[b] * 100 + kc * 10 + kk];
  }
  __syncthreads();
  int ef4 = blockIdx.x * 256 + tid;
  if (ef4 < 2500) {
    float4 acc[16];
#pragma unroll
    for (int b = 0; b < 16; b++) acc[b] = make_float4(0.f, 0.f, 0.f, 0.f);
#pragma unroll
    for (int kk = 0; kk < 10; kk++) {
      float4 w = W4[(kc * 10 + kk) * 2500 + ef4];
#pragma unroll
      for (int b = 0; b < 16; b++) {
        float r = r2s[b][kk];
        acc[b].x = fmaf(r, w.x, acc[b].x);
        acc[b].y = fmaf(r, w.y, acc[b].y);
        acc[b].z = fmaf(r, w.z, acc[b].z);
        acc[b].w = fmaf(r, w.w, acc[b].w);
      }
    }
    float4* o = (float4*)(Wm_p + (long)kc * 320000 + t * 160000);
#pragma unroll
    for (int b = 0; b < 16; b++) o[b * 2500 + ef4] = acc[b];
  }
}

// K1b: Wm = sum over 10 kc partials.  grid (313), block 256
__global__ void k1b_reduce(const float* __restrict__ Wm_p, float* __restrict__ Wm) {
  int i4 = blockIdx.x * 256 + threadIdx.x;
  if (i4 >= 80000) return;
  const float4* P4 = (const float4*)Wm_p;
  float4 o = make_float4(0.f, 0.f, 0.f, 0.f);
#pragma unroll
  for (int j = 0; j < 10; j++) {
    float4 a = P4[(long)j * 80000 + i4];
    o.x += a.x; o.y += a.y; o.z += a.z; o.w += a.w;
  }
  ((float4*)Wm)[i4] = o;
}

// ---------------------------------------------------------------------------
// K2f: fused transpose+cast+MFMA Gram.  grid (NB2, 2), block 256 (4 waves).
__global__ __launch_bounds__(256) void k2f_gram(const float* __restrict__ E_a,
                                                const float* __restrict__ E_b,
                                                float* __restrict__ Gp,
                                                float* __restrict__ CSp) {
  const int t = blockIdx.y, bx = blockIdx.x;
  const float4* E4 = (const float4*)(t ? E_b : E_a);
  __shared__ __align__(16) u16 FRl[4][4][512];   // [rb][ncl][lane*8+elem], 16 KB
  const int tid = threadIdx.x;
  const int wave = tid >> 6, lane = tid & 63, l31 = lane & 31;

  for (int i = tid; i < 8192; i += 256) ((u16*)FRl)[i] = 0;   // rows e>=100 stay 0

  const int ti0 = bx * TPB2;
  const int nt = min(ti0 + TPB2, TPT) - ti0;

  float16 acc0, acc1, acc2, acc3;
#pragma unroll 16
  for (int r = 0; r < 16; r++) { acc0[r] = 0.f; acc1[r] = 0.f; acc2[r] = 0.f; acc3[r] = 0.f; }
  float cs = 0.f;
  float4 st[7];

#define K2F_LOAD(tile)                                          \
  { int n0 = (tile) * 64;                                       \
    _Pragma("unroll")                                           \
    for (int s = 0; s < 7; s++) {                               \
      int i = s * 256 + tid;                                    \
      float4 v = make_float4(0.f, 0.f, 0.f, 0.f);               \
      if (i < 1600) {                                           \
        int nl = i / 25, e4 = i - nl * 25;                      \
        int n = n0 + nl;                                        \
        if (n < NE) v = E4[(long)n * 25 + e4];                  \
      }                                                         \
      st[s] = v;                                                \
    } }

#define K2F_WRITE()                                             \
  { _Pragma("unroll")                                           \
    for (int s = 0; s < 7; s++) {                               \
      int i = s * 256 + tid;                                    \
      if (i < 1600) {                                           \
        int nl = i / 25, e4 = i - nl * 25;                      \
        int half = (nl >> 3) & 1, ncl = nl >> 4, elem = nl & 7; \
        _Pragma("unroll")                                       \
        for (int j = 0; j < 4; j++) {                           \
          int e = e4 * 4 + j;                                   \
          FRl[e >> 5][ncl][((e & 31) + 32 * half) * 8 + elem] = f2bf(f4get(st[s], j)); \
        } } } }

  __syncthreads();            // zeros visible
  K2F_LOAD(ti0);
  K2F_WRITE();
  __syncthreads();

  for (int tt = 0; tt < nt; tt++) {
    if (tt + 1 < nt) K2F_LOAD(ti0 + tt + 1);
#pragma unroll
    for (int ncl = 0; ncl < 4; ncl++) {
      const u16* pf = &FRl[0][ncl][lane * 8];
      short8 f0 = *(const short8*)pf;
      short8 f1 = *(const short8*)(pf + 2048);
      short8 f2 = *(const short8*)(pf + 4096);
      short8 f3 = *(const short8*)(pf + 6144);
      short8 av = *(const short8*)(pf + wave * 2048);
      acc0 = __builtin_amdgcn_mfma_f32_32x32x16_bf16(av, f0, acc0, 0, 0, 0);
      acc1 = __builtin_amdgcn_mfma_f32_32x32x16_bf16(av, f1, acc1, 0, 0, 0);
      acc2 = __builtin_amdgcn_mfma_f32_32x32x16_bf16(av, f2, acc2, 0, 0, 0);
      acc3 = __builtin_amdgcn_mfma_f32_32x32x16_bf16(av, f3, acc3, 0, 0, 0);
#pragma unroll
      for (int j = 0; j < 8; j++) cs += bf2f((u16)av[j]);
    }
    __syncthreads();
    if (tt + 1 < nt) K2F_WRITE();
    __syncthreads();
  }

  float* gp = Gp + ((long)t * NB2 + bx) * 10000;
#pragma unroll 16
  for (int r = 0; r < 16; r++) {
    int m = (r & 3) + 8 * (r >> 2) + 4 * (lane >> 5);   // verified C/D mapping
    int e = wave * 32 + m;
    if (e < 100) {
      gp[e * 100 + l31] = acc0[r];
      gp[e * 100 + 32 + l31] = acc1[r];
      gp[e * 100 + 64 + l31] = acc2[r];
      if (l31 < 4) gp[e * 100 + 96 + l31] = acc3[r];
    }
  }
  cs += __shfl_xor(cs, 32);
  int row = wave * 32 + l31;
  if (lane < 32 && row < 100)
    CSp[((long)t * NB2 + bx) * 100 + row] = cs;
}

// ---------------------------------------------------------------------------
// K2 fallback: VALU Gram (only if workspace too small)
__global__ __launch_bounds__(256, 4) void k2_gram(const float* __restrict__ E_a,
                                                  const float* __restrict__ E_b,
                                                  float* __restrict__ Gp,
                                                  float* __restrict__ CSp,
                                                  int NB, int RPB) {
  const int t = blockIdx.y;
  const float* E = t ? E_b : E_a;
  const float4* E4 = (const float4*)E;
  __shared__ float sm[32][128];
  const int tid = threadIdx.x;
  const int bx = blockIdx.x;
  int r0 = bx * RPB;
  int rend = min(r0 + RPB, NE);
  for (int i = tid; i < 32 * 28; i += 256) {
    int r = i / 28;
    sm[r][100 + (i - r * 28)] = 0.f;
  }
  float acc[8][8];
#pragma unroll
  for (int i = 0; i < 8; i++)
#pragma unroll
    for (int j = 0; j < 8; j++) acc[i][j] = 0.f;
  float cs = 0.f;
  const int ty = tid >> 4, tx = tid & 15;
  for (int base = r0; base < rend; base += 32) {
    int cnt = min(32, rend - base);
    __syncthreads();
    for (int i = tid; i < 800; i += 256) {
      int r = i / 25, c4 = i - r * 25;
      float4 v = make_float4(0.f, 0.f, 0.f, 0.f);
      if (r < cnt) v = E4[(long)(base + r) * 25 + c4];
      *(float4*)&sm[r][c4 * 4] = v;
    }
    __syncthreads();
#pragma unroll 2
    for (int r = 0; r < 32; r++) {
      float4 a0 = *(const float4*)&sm[r][ty * 8];
      float4 a1 = *(const float4*)&sm[r][ty * 8 + 4];
      float4 b0 = *(const float4*)&sm[r][tx * 8];
      float4 b1 = *(const float4*)&sm[r][tx * 8 + 4];
      float av[8] = {a0.x, a0.y, a0.z, a0.w, a1.x, a1.y, a1.z, a1.w};
      float bv[8] = {b0.x, b0.y, b0.z, b0.w, b1.x, b1.y, b1.z, b1.w};
#pragma unroll
      for (int i = 0; i < 8; i++)
#pragma unroll
        for (int j = 0; j < 8; j++) acc[i][j] = fmaf(av[i], bv[j], acc[i][j]);
    }
    if (tid < 100) {
#pragma unroll 4
      for (int r = 0; r < 32; r++) cs += sm[r][tid];
    }
  }
  float* gp = Gp + ((long)t * NB + bx) * 10000;
#pragma unroll
  for (int i = 0; i < 8; i++) {
    int e = ty * 8 + i;
    if (e < 100) {
#pragma unroll
      for (int j = 0; j < 8; j++) {
        int ep = tx * 8 + j;
        if (ep < 100) gp[e * 100 + ep] = acc[i][j];
      }
    }
  }
  if (tid < 100) CSp[((long)t * NB + bx) * 100 + tid] = cs;
}

// ---------------------------------------------------------------------------
// K3a/K3b: tree reduce of Gram + colsum partials
__global__ void k3a_reduce(const float* __restrict__ Gp, const float* __restrict__ CSp,
                           float* __restrict__ Gp2, float* __restrict__ CSp2,
                           int NB, int seg) {
  int chunk = blockIdx.x, slice = blockIdx.y, t = blockIdx.z;
  int nb0 = slice * seg;
  int nb1 = min(nb0 + seg, NB);
  int idx = chunk * 256 + threadIdx.x;
  if (idx < 10000) {
    float s = 0.f;
    const float* p = Gp + ((long)t * NB + nb0) * 10000 + idx;
    for (int nb = nb0; nb < nb1; nb++, p += 10000) s += *p;
    Gp2[(t * SLICES + slice) * 10000 + idx] = s;
  }
  if (chunk == 0 && threadIdx.x < 100) {
    float s = 0.f;
    const float* p = CSp + ((long)t * NB + nb0) * 100 + threadIdx.x;
    for (int nb = nb0; nb < nb1; nb++, p += 100) s += *p;
    CSp2[(t * SLICES + slice) * 100 + threadIdx.x] = s;
  }
}

__global__ void k3b_reduce(const float* __restrict__ Gp2, const float* __restrict__ CSp2,
                           float* __restrict__ G, float* __restrict__ CS) {
  int chunk = blockIdx.x, t = blockIdx.y;
  int idx = chunk * 256 + threadIdx.x;
  if (idx < 10000) {
    float s = 0.f;
    const float* p = Gp2 + (long)t * SLICES * 10000 + idx;
#pragma unroll
    for (int sl = 0; sl < SLICES; sl++) s += p[sl * 10000];
    G[t * 10000 + idx] = s;
  }
  if (chunk == 0 && threadIdx.x < 100) {
    float s = 0.f;
    const float* p = CSp2 + (long)t * SLICES * 100 + threadIdx.x;
#pragma unroll
    for (int sl = 0; sl < SLICES; sl++) s += p[sl * 100];
    CS[t * 100 + threadIdx.x] = s;
  }
}

// ---------------------------------------------------------------------------
// K6g: BN3 stats as batched quadratic forms.  grid (13, 10, 2), block 128.
// Column j=(b,f): qf[t][ci][j] = sum_{e' in ci} sum_e G[e'][e] y[e'] y[e],
// s2q[t][ci][j] = sum_{e' in ci} CS[e'] y[e'],  y[e] = Wm[t][b][e][f].
// G rows staged in LDS (broadcast reads); 10 y in regs; 100 streamed loads.
__global__ __launch_bounds__(128) void k6g_qf(const float* __restrict__ Wm,
                                              const float* __restrict__ G,
                                              const float* __restrict__ CS,
                                              float* __restrict__ qf,
                                              float* __restrict__ s2q) {
  const int cx = blockIdx.x, ci = blockIdx.y, t = blockIdx.z;
  const int tid = threadIdx.x;
  __shared__ float Gl[QCI][100];
  __shared__ float CSl[QCI];
  for (int i = tid; i < QCI * 100; i += 128) {
    int k = i / 100, e = i - k * 100;
    Gl[k][e] = G[t * 10000 + (ci * QCI + k) * 100 + e];
  }
  if (tid < QCI) CSl[tid] = CS[t * 100 + ci * QCI + tid];
  __syncthreads();
  int j = cx * 128 + tid;
  if (j >= 1600) return;
  int b = j / 100, f = j - b * 100;
  const float* Y = Wm + t * 160000 + b * 10000 + f;
  float yci[QCI];
  float cs2 = 0.f;
#pragma unroll
  for (int k = 0; k < QCI; k++) {
    yci[k] = Y[(ci * QCI + k) * 100];
    cs2 = fmaf(CSl[k], yci[k], cs2);
  }
  float acc = 0.f;
#pragma unroll 4
  for (int e = 0; e < 100; e++) {
    float ye = Y[e * 100];
    float i0 = 0.f, i1 = 0.f;
#pragma unroll
    for (int k = 0; k < QCI; k += 2) {
      i0 = fmaf(Gl[k][e], yci[k], i0);
      i1 = fmaf(Gl[k + 1][e], yci[k + 1], i1);
    }
    acc = fmaf(i0 + i1, ye, acc);
  }
  qf[((long)t * QCI + ci) * QNJ + j] = acc;
  s2q[((long)t * QCI + ci) * QNJ + j] = cs2;
}

// ---------------------------------------------------------------------------
// K4a: gather+BN0 (tiny redundant) + coalesced matvec -> traw; fold qf/s2q ci-sums.
// grid (32) = (t,b), block 128.
__global__ __launch_bounds__(128) void k4a_traw(const float* __restrict__ E_a,
                                                const float* __restrict__ E_b,
                                                const int* __restrict__ h_idx,
                                                const float* __restrict__ Wm,
                                                const float* __restrict__ g0r, const float* __restrict__ b0r,
                                                const float* __restrict__ g0i, const float* __restrict__ b0i,
                                                const float* __restrict__ qf,
                                                const float* __restrict__ s2q,
                                                float* __restrict__ traw,
                                                float* __restrict__ s1pp,
                                                float* __restrict__ s2pp) {
  int bid = blockIdx.x;
  int t = bid >> 4, b = bid & 15;
  const float4* E4 = (const float4*)(t ? E_b : E_a);
  const float* g0 = t ? g0i : g0r;
  const float* be0 = t ? b0i : b0r;
  __shared__ float hrows[1600], x[100];
  int tid = threadIdx.x;
  for (int i = tid; i < 400; i += 128) {
    int b2 = i / 25, e4 = i - b2 * 25;
    float4 v = E4[(long)h_idx[b2] * 25 + e4];
    *(float4*)&hrows[b2 * 100 + e4 * 4] = v;
  }
  __syncthreads();
  if (tid < 100) {
    float m = 0.f, s = 0.f;
#pragma unroll
    for (int b2 = 0; b2 < 16; b2++) { float v = hrows[b2 * 100 + tid]; m += v; s += v * v; }
    m *= (1.f / 16.f);
    float var = s * (1.f / 16.f) - m * m;
    x[tid] = (hrows[b * 100 + tid] - m) * rsqrtf(var + EPS_F) * g0[tid] + be0[tid];
  }
  __syncthreads();
  if (tid < 100) {
    const float* W = Wm + t * 160000 + b * 10000 + tid;
    float s = 0.f;
    for (int e = 0; e < 100; e++) s = fmaf(x[e], W[e * 100], s);
    traw[t * 1600 + b * 100 + tid] = s;
    // fold ci-partials so k4b only sums over b
    float s1 = 0.f, s2 = 0.f;
    const float* pq = qf + (long)t * QCI * QNJ + b * 100 + tid;
    const float* ps = s2q + (long)t * QCI * QNJ + b * 100 + tid;
#pragma unroll
    for (int ci = 0; ci < QCI; ci++) {
      s1 += pq[ci * QNJ];
      s2 += ps[ci * QNJ];
    }
    s1pp[t * 1600 + b * 100 + tid] = s1;
    s2pp[t * 1600 + b * 100 + tid] = s2;
  }
}

// ---------------------------------------------------------------------------
// K4b: BN1 + Mobius + alpha/beta + w01 + c.  grid (1), block 256.
__global__ __launch_bounds__(256) void k4b_mid(const float* __restrict__ traw,
                                               const int* __restrict__ r_idx,
                                               const float* __restrict__ g1r, const float* __restrict__ b1r,
                                               const float* __restrict__ g1i, const float* __restrict__ b1i,
                                               const float* __restrict__ R_re, const float* __restrict__ R_im,
                                               const float* __restrict__ s1pp, const float* __restrict__ s2pp,
                                               const float* __restrict__ gEa, const float* __restrict__ bEa,
                                               const float* __restrict__ gEb, const float* __restrict__ bEb,
                                               float* __restrict__ w01, float* __restrict__ c) {
  int tid = threadIdx.x;
  __shared__ float tr[3200], t01l[3200];
  __shared__ float sca[200], shl[200], al[200], be[200];
  for (int i = tid; i < 3200; i += 256) tr[i] = traw[i];
  __syncthreads();
  if (tid < 200) {
    int tt = tid / 100, f = tid - tt * 100;
    float m = 0.f, s = 0.f;
#pragma unroll
    for (int b = 0; b < 16; b++) { float v = tr[tt * 1600 + b * 100 + f]; m += v; s += v * v; }
    m *= (1.f / 16.f);
    float var = s * (1.f / 16.f) - m * m;
    float g = tt ? g1i[f] : g1r[f];
    float bb = tt ? b1i[f] : b1r[f];
    float sc = rsqrtf(var + EPS_F) * g;
    sca[tid] = sc; shl[tid] = bb - m * sc;
    float s1 = 0.f, s2 = 0.f;
#pragma unroll
    for (int b2 = 0; b2 < 16; b2++) {
      s1 += s1pp[tt * 1600 + b2 * 100 + f];
      s2 += s2pp[tt * 1600 + b2 * 100 + f];
    }
    float mean = s2 * (1.f / 800000.f);
    float var2 = s1 * (1.f / 800000.f) - mean * mean;
    float gE = tt ? gEb[f] : gEa[f];
    float bE = tt ? bEb[f] : bEa[f];
    float aa = rsqrtf(var2 + EPS_F) * gE;
    al[tid] = aa; be[tid] = bE - mean * aa;
  }
  __syncthreads();
  for (int i = tid; i < 1600; i += 256) {
    int b = i / 100, f = i - b * 100;
    float va = tr[b * 100 + f] * sca[f] + shl[f];
    float vb = tr[1600 + b * 100 + f] * sca[100 + f] + shl[100 + f];
    int base = r_idx[b] * 400 + f;
    float ra0 = R_re[base],       ra1 = R_im[base];
    float rb0 = R_re[base + 100], rb1 = R_im[base + 100];
    float rc0 = R_re[base + 200], rc1 = R_im[base + 200];
    float rd0 = R_re[base + 300], rd1 = R_im[base + 300];
    float top0 = va * ra0 - vb * ra1 + rb0;
    float top1 = va * ra1 + vb * ra0 + rb1;
    float bot0 = va * rc0 - vb * rc1 + rd0;
    float bot1 = va * rc1 + vb * rc0 + rd1;
    float den = bot0 * bot0 + bot1 * bot1;
    float t0 = (top0 * bot0 + top1 * bot1) / den;
    float t1 = (top1 * bot0 - top0 * bot1) / den;
    t01l[i] = t0; t01l[1600 + i] = t1;
    w01[i] = t0 * al[f];
    w01[1600 + i] = t1 * al[100 + f];
  }
  __syncthreads();
  if (tid < 16) {
    float cc = 0.f;
    for (int f = 0; f < 100; f++) {
      cc += t01l[tid * 100 + f] * be[f] + t01l[1600 + tid * 100 + f] * be[100 + f];
    }
    c[tid] = cc;
  }
}

// ---------------------------------------------------------------------------
// K4c: u[t][e][b] = sum_f w01[t][b][f] * Wm[t][b][e][f].  grid (32), block 256.
__global__ __launch_bounds__(256) void k4c_u(const float* __restrict__ Wm,
                                             const float* __restrict__ w01,
                                             float* __restrict__ u) {
  int bid = blockIdx.x;
  int t = bid >> 4, b = bid & 15;
  __shared__ float w[100];
  __shared__ float Wl[100 * 101];
  int tid = threadIdx.x;
  if (tid < 100) w[tid] = w01[t * 1600 + b * 100 + tid];
  const float4* W4 = (const float4*)(Wm + t * 160000 + b * 10000);
  for (int i = tid; i < 2500; i += 256) {
    float4 v = W4[i];
    int e = (i * 4) / 100, f0 = (i * 4) - e * 100;
    float* dst = &Wl[e * 101 + f0];
    dst[0] = v.x; dst[1] = v.y; dst[2] = v.z; dst[3] = v.w;
  }
  __syncthreads();
  if (tid < 100) {
    const float* row = &Wl[tid * 101];
    float s = 0.f;
    for (int f = 0; f < 100; f++) s = fmaf(w[f], row[f], s);
    u[(t * 100 + tid) * 16 + b] = s;
  }
}

// ---------------------------------------------------------------------------
// K9: score = sigmoid(c + u_a·E_a + u_b·E_b).  grid (196), block 256
__global__ __launch_bounds__(256) void k9_score(const float* __restrict__ E_a,
                                                const float* __restrict__ E_b,
                                                const float* __restrict__ u,
                                                const float* __restrict__ c,
                                                float* __restrict__ out) {
  int n = blockIdx.x * 256 + threadIdx.x;
  if (n >= NE) return;
  const float4* Ea4 = (const float4*)E_a;
  const float4* Eb4 = (const float4*)E_b;
  float acc[16];
#pragma unroll
  for (int b = 0; b < 16; b++) acc[b] = 0.f;
  for (int e4 = 0; e4 < 25; e4++) {
    float4 va = Ea4[n * 25 + e4];
    float4 vb = Eb4[n * 25 + e4];
    const float* ua = u + e4 * 64;
    const float* ub = u + 1600 + e4 * 64;
#pragma unroll
    for (int j = 0; j < 4; j++) {
      float fa = f4get(va, j);
      float fb = f4get(vb, j);
#pragma unroll
      for (int b = 0; b < 16; b++) {
        acc[b] = fmaf(ua[j * 16 + b], fa, acc[b]);
        acc[b] = fmaf(ub[j * 16 + b], fb, acc[b]);
      }
    }
  }
#pragma unroll
  for (int b = 0; b < 16; b++) {
    float x = acc[b] + c[b];
    out[b * NE + n] = 1.f / (1.f + expf(-x));
  }
}

// ---------------------------------------------------------------------------
extern "C" void kernel_launch(void* const* d_in, const int* in_sizes, int n_in,
                              void* d_out, int out_size, void* d_ws, size_t ws_size,
                              hipStream_t stream) {
  const int* h_idx = (const int*)d_in[0];
  const int* r_idx = (const int*)d_in[1];
  const float* E_a = (const float*)d_in[2];
  const float* E_b = (const float*)d_in[3];
  const float* R_re = (const float*)d_in[4];
  const float* R_im = (const float*)d_in[5];
  const float* R2 = (const float*)d_in[6];
  const float* W_re = (const float*)d_in[7];
  const float* W_im = (const float*)d_in[8];
  const float* g0r = (const float*)d_in[9];
  const float* b0r = (const float*)d_in[10];
  const float* g1r = (const float*)d_in[11];
  const float* b1r = (const float*)d_in[12];
  const float* g0i = (const float*)d_in[13];
  const float* b0i = (const float*)d_in[14];
  const float* g1i = (const float*)d_in[15];
  const float* b1i = (const float*)d_in[16];
  const float* gEa = (const float*)d_in[17];
  const float* bEa = (const float*)d_in[18];
  const float* gEb = (const float*)d_in[19];
  const float* bEb = (const float*)d_in[20];
  float* out = (float*)d_out;
  float* ws = (float*)d_ws;

  // fixed regions (422,776 floats)
  float* Wm = ws;                    // [2][16][10000]   320000
  float* G = Wm + 320000;            // [2][10000]        20000
  float* CS = G + 20000;             // [2][100]            200
  float* u = CS + 200;               // [2][100][16]       3200
  float* c = u + 3200;               //                      16
  float* qf = c + 16;                // [2][QCI][QNJ]     33280
  float* s2q = qf + 33280;           // [2][QCI][QNJ]     33280
  float* traw = s2q + 33280;         // [2][16][100]       3200
  float* w01 = traw + 3200;          // [2][16][100]       3200
  float* s1pp = w01 + 3200;          // [2][16][100]       3200
  float* s2pp = s1pp + 3200;         // [2][16][100]       3200
  const long fixed = 422776;

  float* un = ws + fixed;
  long avail = (long)(ws_size / 4);
  long unionFloats = avail - fixed - 64;

  // k1 scratch overlaps union head (lifetime ends before gram)
  float* Wm_p = un;                  // 3,200,000 floats
  int splitK1 = (unionFloats >= 3200000);
  if (splitK1) {
    hipLaunchKernelGGL(k1a_wm, dim3(10, 10, 2), dim3(256), 0, stream, W_re, W_im, R2, r_idx, Wm_p);
    hipLaunchKernelGGL(k1b_reduce, dim3(313), dim3(256), 0, stream, Wm_p, Wm);
  } else {
    hipLaunchKernelGGL(k1_wm, dim3(40, 2), dim3(256), 0, stream, W_re, W_im, R2, r_idx, Wm);
  }

  const long needMain = 323200 + (long)NB2 * 20200;   // Gp2/CSp2 + Gp/CSp
  if (unionFloats >= needMain) {
    float* Gp2 = un;
    float* CSp2 = Gp2 + 320000;
    float* Gp = CSp2 + 3200;
    float* CSp = Gp + (long)NB2 * 20000;
    int seg = (NB2 + SLICES - 1) / SLICES;
    hipLaunchKernelGGL(k2f_gram, dim3(NB2, 2), dim3(256), 0, stream, E_a, E_b, Gp, CSp);
    hipLaunchKernelGGL(k3a_reduce, dim3(40, SLICES, 2), dim3(256), 0, stream,
                       Gp, CSp, Gp2, CSp2, NB2, seg);
    hipLaunchKernelGGL(k3b_reduce, dim3(40, 2), dim3(256), 0, stream, Gp2, CSp2, G, CS);
  } else {
    float* Gp2 = un;
    float* CSp2 = Gp2 + 320000;
    float* Gp = CSp2 + 3200;
    long room = (unionFloats - 323200) / 20200;
    int NB = room < 360 ? (int)room : 360;
    if (NB < 1) NB = 1;
    int RPB = (NE + NB - 1) / NB;
    int seg = (NB + SLICES - 1) / SLICES;
    float* CSp = Gp + (long)NB * 20000;
    hipLaunchKernelGGL(k2_gram, dim3(NB, 2), dim3(256), 0, stream, E_a, E_b, Gp, CSp, NB, RPB);
    hipLaunchKernelGGL(k3a_reduce, dim3(40, SLICES, 2), dim3(256), 0, stream,
                       Gp, CSp, Gp2, CSp2, NB, seg);
    hipLaunchKernelGGL(k3b_reduce, dim3(40, 2), dim3(256), 0, stream, Gp2, CSp2, G, CS);
  }

  hipLaunchKernelGGL(k6g_qf, dim3(13, QCI, 2), dim3(128), 0, stream, Wm, G, CS, qf, s2q);
  hipLaunchKernelGGL(k4a_traw, dim3(32), dim3(128), 0, stream, E_a, E_b, h_idx, Wm,
                     g0r, b0r, g0i, b0i, qf, s2q, traw, s1pp, s2pp);
  hipLaunchKernelGGL(k4b_mid, dim3(1), dim3(256), 0, stream, traw, r_idx,
                     g1r, b1r, g1i, b1i, R_re, R_im, s1pp, s2pp,
                     gEa, bEa, gEb, bEb, w01, c);
  hipLaunchKernelGGL(k4c_u, dim3(32), dim3(256), 0, stream, Wm, w01, u);
  hipLaunchKernelGGL(k9_score, dim3((NE + 255) / 256), dim3(256), 0, stream,
                     E_a, E_b, u, c, out);
}